// Round 4
// baseline (926.821 us; speedup 1.0000x reference)
//
#include <hip/hip_runtime.h>
#include <hip/hip_bf16.h>

typedef __bf16 bf16x8 __attribute__((ext_vector_type(8)));
typedef __bf16 bf16x4 __attribute__((ext_vector_type(4)));
typedef float  f32x16 __attribute__((ext_vector_type(16)));

#define MFMA __builtin_amdgcn_mfma_f32_32x32x16_bf16
#define BM 128           // batch rows per block (4 batch-tiles of 32)

// ---------------- weight prepack ----------------
// A-operand = W^T for v_mfma_f32_32x32x16_bf16.
// A[m][k]: m = lane&31 (out-feature), k = (lane>>5)*8 + j.
// Unit order: unit = k16*NU + mt  (NU = N/32), addr(uint4) = base + unit*64 + lane.
// elem j = W[k16*16 + (lane>>5)*8 + j][mt*32 + (lane&31)]
struct PrepParams {
    const float* src[9];
    int Kt[9];       // K/32
    int Mg[9];       // N/128 (col groups)
    int N[9];
    int blkEnd[9];
    int unitBase[9];
};

__global__ void __launch_bounds__(256)
prep_weights(PrepParams p, uint4* __restrict__ dst) {
    __shared__ float tile[32][128];
    int b = blockIdx.x;
    int w = 0;
    while (b >= p.blkEnd[w]) ++w;
    int local = b - ((w == 0) ? 0 : p.blkEnd[w - 1]);
    int mgc = p.Mg[w];
    int kt = local / mgc;
    int mg = local - kt * mgc;
    const float* src = p.src[w];
    int N = p.N[w];
    int NU = N >> 5;
    int t = threadIdx.x;

    int row0 = kt * 32, col0 = mg * 128;
#pragma unroll
    for (int i = 0; i < 4; ++i) {
        int e4 = t + i * 256;            // 1024 float4 in 32x128 tile
        int r = e4 >> 5;
        int c4 = e4 & 31;
        float4 v = *(const float4*)&src[(size_t)(row0 + r) * N + col0 + c4 * 4];
        *(float4*)&tile[r][c4 * 4] = v;
    }
    __syncthreads();

#pragma unroll
    for (int rep = 0; rep < 2; ++rep) {
        int ul = t + rep * 256;          // 512 units-lanes per block
        int lane = ul & 63;
        int kcl = (ul >> 6) & 1;
        int mtl = ul >> 7;               // 0..3
        int mt = mg * 4 + mtl;
        int k16 = kt * 2 + kcl;
        int gUnit = p.unitBase[w] + (k16 * NU + mt) * 64 + lane;
        int lr = kcl * 16 + ((lane >> 5) << 3);
        int lc = mtl * 32 + (lane & 31);
        alignas(16) unsigned short u8[8];
#pragma unroll
        for (int j = 0; j < 8; ++j)
            u8[j] = __builtin_bit_cast(unsigned short, (__bf16)tile[lr + j][lc]);
        dst[gUnit] = *(const uint4*)u8;
    }
}

// ---------------- fused MLP ----------------
struct MlpParams {
    const float* X[3];
    const unsigned short* Wp[3];
    const float* B1[3];
    const float* B2[3];
    const float* B3[3];
    int dIn[3];
    int Nt[3];
    int rowOff[3];
    int blkStart[3];
};

__device__ __forceinline__ float sigmoidf(float z) {
    return __builtin_amdgcn_rcpf(
        1.0f + __builtin_amdgcn_exp2f(-1.442695040888963f * z));
}

// XOR-swizzle on byte offsets in the 128KB act buffer (1024-B rows): flip
// granule bits [8:4] with row&31 -> all strided-row accesses conflict-free.
__device__ __forceinline__ unsigned swz(unsigned o) {
    return o ^ (((o >> 10) & 31) << 4);
}

// Register-streamed layer: A (private per wave) global->reg with depth-4
// rotating prefetch (static indices, fully unrolled); B from swizzled LDS
// act rows. NO barriers in the K-loop: act is read-only during the layer,
// A-units are wave-exclusive (wave owns mtiles wave*MT..+MT-1 x all 4 bts).
// C/D: batchcol = lane&31, featrow = (reg&3)+8*(reg>>2)+4*(lane>>5).
template <int K16, int NU, int MT, bool TO_LDS>
__device__ __forceinline__ void layerR(
    char* __restrict__ act,
    const uint4* __restrict__ W,
    const float* __restrict__ bias,
    int wave, int lane)
{
    const int lr = lane & 31;
    const int half = lane >> 5;
    const unsigned xm = (unsigned)lr << 4;                 // swizzle mask
    const unsigned bo = (unsigned)lr * 1024u + (unsigned)half * 16u;

    f32x16 acc[MT][4];
#pragma unroll
    for (int m = 0; m < MT; ++m)
#pragma unroll
        for (int bt = 0; bt < 4; ++bt)
#pragma unroll
            for (int e = 0; e < 16; ++e) acc[m][bt][e] = 0.f;

    const uint4* ap = W + (size_t)(wave * MT) * 64 + lane;

    bf16x8 aPf[4][MT];                    // depth-4 ring (K16 >= 4 always)
#pragma unroll
    for (int d = 0; d < 4; ++d)
#pragma unroll
        for (int m = 0; m < MT; ++m)
            aPf[d][m] = *(const bf16x8*)(ap + (size_t)(d * NU + m) * 64);

#pragma unroll
    for (int k = 0; k < K16; ++k) {
        bf16x8 b[4];
#pragma unroll
        for (int bt = 0; bt < 4; ++bt) {
            unsigned o = bo + (unsigned)bt * 32768u + (unsigned)k * 32u;
            b[bt] = *(const bf16x8*)(act + (o ^ xm));
        }
        bf16x8 av[MT];
#pragma unroll
        for (int m = 0; m < MT; ++m) av[m] = aPf[k & 3][m];
        if (k + 4 < K16) {
#pragma unroll
            for (int m = 0; m < MT; ++m)
                aPf[k & 3][m] =
                    *(const bf16x8*)(ap + (size_t)((k + 4) * NU + m) * 64);
        }
#pragma unroll
        for (int m = 0; m < MT; ++m)
#pragma unroll
            for (int bt = 0; bt < 4; ++bt)
                acc[m][bt] = MFMA(av[m], b[bt], acc[m][bt], 0, 0, 0);
    }

    __syncthreads();   // all waves' act reads done before in-place overwrite

#pragma unroll
    for (int m = 0; m < MT; ++m) {
        int mt = wave * MT + m;
#pragma unroll
        for (int g = 0; g < 4; ++g) {
            int f0 = mt * 32 + g * 8 + half * 4;   // 4 consecutive features
            float4 bv = *(const float4*)(bias + f0);
#pragma unroll
            for (int bt = 0; bt < 4; ++bt) {
                int r = bt * 32 + lr;
                float s0 = sigmoidf(acc[m][bt][g * 4 + 0] + bv.x);
                float s1 = sigmoidf(acc[m][bt][g * 4 + 1] + bv.y);
                float s2 = sigmoidf(acc[m][bt][g * 4 + 2] + bv.z);
                float s3 = sigmoidf(acc[m][bt][g * 4 + 3] + bv.w);
                if constexpr (TO_LDS) {
                    bf16x4 h4 = {(__bf16)s0, (__bf16)s1, (__bf16)s2, (__bf16)s3};
                    *(bf16x4*)(act + swz((unsigned)r * 1024u + (unsigned)f0 * 2u)) = h4;
                } else {
                    *(float4*)(act + swz((unsigned)r * 1024u + (unsigned)f0 * 4u)) =
                        make_float4(s0, s1, s2, s3);
                }
            }
        }
    }
    __syncthreads();   // writes visible before next phase reads
}

__global__ void __launch_bounds__(512, 2)   // 8 waves, 1 block/CU (128 KB LDS)
mlp_fused(MlpParams p, float* __restrict__ out) {
    extern __shared__ char act[];           // 128 rows x 1024 B, XOR-swizzled

    // bijective chunked XCD swizzle (m204): same-type blocks cluster per XCD
    int nwg = gridDim.x;
    int bid = blockIdx.x;
    int q = nwg >> 3, r8 = nwg & 7;
    int xcd = bid & 7, lid = bid >> 3;
    int b = (xcd < r8 ? xcd * (q + 1) : r8 * (q + 1) + (xcd - r8) * q) + lid;

    int t = (b >= p.blkStart[1]) + (b >= p.blkStart[2]);
    int blk = b - p.blkStart[t];
    int dIn = p.dIn[t];
    int Nt = p.Nt[t];
    int row0 = blk * BM;
    const float* X = p.X[t];
    const uint4* W1u = (const uint4*)p.Wp[t];
    const uint4* W2u = W1u + ((size_t)dIn * 512 >> 3);
    const uint4* W3u = W2u + ((size_t)512 * 512 >> 3);

    int tid = threadIdx.x;
    int wave = tid >> 6;
    int lane = tid & 63;

    // ---- stage X (fp32 global -> bf16 swizzled LDS rows [128][dIn]) ----
    int d4 = dIn >> 2;               // float4 per row (16/32/64)
    int s4 = 31 - __clz(d4);
    int nf4 = BM * d4;
    for (int i = tid; i < nf4; i += 512) {
        int r = i >> s4;
        int c4 = i & (d4 - 1);
        int grow = row0 + r;
        float4 v = make_float4(0.f, 0.f, 0.f, 0.f);
        if (grow < Nt) v = ((const float4*)X)[(size_t)grow * d4 + c4];
        ushort4 u;
        u.x = __builtin_bit_cast(unsigned short, (__bf16)v.x);
        u.y = __builtin_bit_cast(unsigned short, (__bf16)v.y);
        u.z = __builtin_bit_cast(unsigned short, (__bf16)v.z);
        u.w = __builtin_bit_cast(unsigned short, (__bf16)v.w);
        unsigned o = (unsigned)r * 1024u + (unsigned)c4 * 8u;
        *(ushort4*)(act + swz(o)) = u;
    }
    __syncthreads();

    // L1: X -> H1 in place (K16 = dIn/16, compile-time per type)
    if (t == 0)      layerR<4,  16, 2, true >(act, W1u, p.B1[0], wave, lane);
    else if (t == 1) layerR<8,  16, 2, true >(act, W1u, p.B1[1], wave, lane);
    else             layerR<16, 16, 2, true >(act, W1u, p.B1[2], wave, lane);
    // L2: H1 -> H2 in place
    layerR<32, 16, 2, true >(act, W2u, p.B2[t], wave, lane);
    // L3: H2 -> f32 staging in act
    layerR<32,  8, 1, false>(act, W3u, p.B3[t], wave, lane);

    // ---- coalesced output store: 128 rows x 256 f32, full 1KB rows ----
    float* gOut = out + (size_t)(p.rowOff[t] + row0) * 256;
    for (int i = tid; i < BM * 64; i += 512) {   // 8192 float4
        int r = i >> 6;
        int c4 = i & 63;
        if (row0 + r < Nt) {
            unsigned o = (unsigned)r * 1024u + (unsigned)c4 * 16u;
            *(float4*)(gOut + r * 256 + c4 * 4) = *(const float4*)(act + swz(o));
        }
    }
}

// ---------------- launch ----------------
extern "C" void kernel_launch(void* const* d_in, const int* in_sizes, int n_in,
                              void* d_out, int out_size, void* d_ws, size_t ws_size,
                              hipStream_t stream) {
    const int IN0[3] = {64, 128, 256};
    const int CNT[3] = {100000, 80000, 60000};

    // ---- prepack weights into ws (bf16, unit-ordered A fragments) ----
    PrepParams pp;
    int blocks = 0, ubase = 0;
    for (int t = 0; t < 3; ++t) {
        int Ks[3] = {IN0[t], 512, 512};
        int Ns[3] = {512, 512, 256};
        for (int l = 0; l < 3; ++l) {
            int w = t * 3 + l;
            pp.src[w] = (const float*)d_in[4 + t * 6 + l * 2];
            pp.Kt[w] = Ks[l] >> 5;
            pp.Mg[w] = Ns[l] >> 7;
            pp.N[w] = Ns[l];
            pp.unitBase[w] = ubase;
            blocks += pp.Kt[w] * pp.Mg[w];
            pp.blkEnd[w] = blocks;
            ubase += (Ks[l] * Ns[l]) >> 3;
        }
    }
    prep_weights<<<dim3(blocks), dim3(256), 0, stream>>>(pp, (uint4*)d_ws);

    // ---- fused MLP ----
    MlpParams mp;
    int woff = 0, roff = 0, boff = 0;
    for (int t = 0; t < 3; ++t) {
        mp.X[t] = (const float*)d_in[t];
        mp.Wp[t] = (const unsigned short*)d_ws + woff;
        mp.B1[t] = (const float*)d_in[4 + t * 6 + 1];
        mp.B2[t] = (const float*)d_in[4 + t * 6 + 3];
        mp.B3[t] = (const float*)d_in[4 + t * 6 + 5];
        mp.dIn[t] = IN0[t];
        mp.Nt[t] = CNT[t];
        mp.rowOff[t] = roff;
        mp.blkStart[t] = boff;
        woff += IN0[t] * 512 + 512 * 512 + 512 * 256;
        roff += CNT[t];
        boff += (CNT[t] + BM - 1) / BM;
    }
    size_t lds = (size_t)BM * 1024;          // 131,072 B
    mlp_fused<<<dim3(boff), dim3(512), lds, stream>>>(mp, (float*)d_out);
}

// Round 5
// 659.015 us; speedup vs baseline: 1.4064x; 1.4064x over previous
//
#include <hip/hip_runtime.h>
#include <hip/hip_bf16.h>

typedef __bf16 bf16x8 __attribute__((ext_vector_type(8)));
typedef __bf16 bf16x4 __attribute__((ext_vector_type(4)));
typedef float  f32x16 __attribute__((ext_vector_type(16)));

#define MFMA __builtin_amdgcn_mfma_f32_32x32x16_bf16
#define BM 64            // batch rows per block (2 N-tiles of 32)
#define S  520           // bf16 elems per LDS activation row (512 + 8)
#define SF 260           // f32 elems per LDS row for out staging (same 1040 B)

// ---------------- weight prepack (identical to round-0, verified) ----------
// A-operand = W^T for v_mfma_f32_32x32x16_bf16.
// A[m][k]: m = lane&31 (out-feature), k = (lane>>5)*8 + j.
// Packed unit u = unitBase[w] + ((mt*Kc + kc)*64 + lane), Kc = K/16; 8 bf16:
//   elem j = W[kc*16 + (lane>>5)*8 + j][mt*32 + (lane&31)]
struct PrepParams {
    const float* src[9];
    int Kt[9];       // K/32
    int Mg[9];       // N/128 (col groups)
    int N[9];
    int blkEnd[9];
    int unitBase[9];
};

__global__ void __launch_bounds__(256)
prep_weights(PrepParams p, uint4* __restrict__ dst) {
    __shared__ float tile[32][128];
    int b = blockIdx.x;
    int w = 0;
    while (b >= p.blkEnd[w]) ++w;
    int local = b - ((w == 0) ? 0 : p.blkEnd[w - 1]);
    int mgc = p.Mg[w];
    int kt = local / mgc;
    int mg = local - kt * mgc;
    const float* src = p.src[w];
    int N = p.N[w];
    int Kc = p.Kt[w] * 2;
    int t = threadIdx.x;

    int row0 = kt * 32, col0 = mg * 128;
#pragma unroll
    for (int i = 0; i < 4; ++i) {
        int e4 = t + i * 256;            // 1024 float4 in 32x128 tile
        int r = e4 >> 5;
        int c4 = e4 & 31;
        float4 v = *(const float4*)&src[(size_t)(row0 + r) * N + col0 + c4 * 4];
        *(float4*)&tile[r][c4 * 4] = v;
    }
    __syncthreads();

#pragma unroll
    for (int rep = 0; rep < 2; ++rep) {
        int ul = t + rep * 256;          // 512 units per block
        int lane = ul & 63;
        int kcl = (ul >> 6) & 1;
        int mtl = ul >> 7;               // 0..3
        int gUnit = p.unitBase[w] +
                    ((mg * 4 + mtl) * Kc + (kt * 2 + kcl)) * 64 + lane;
        int lr = kcl * 16 + ((lane >> 5) << 3);
        int lc = mtl * 32 + (lane & 31);
        alignas(16) unsigned short u8[8];
#pragma unroll
        for (int j = 0; j < 8; ++j)
            u8[j] = __builtin_bit_cast(unsigned short, (__bf16)tile[lr + j][lc]);
        dst[gUnit] = *(const uint4*)u8;
    }
}

// ---------------- fused MLP ----------------
struct MlpParams {
    const float* X[3];
    const unsigned short* Wp[3];
    const float* B1[3];
    const float* B2[3];
    const float* B3[3];
    int dIn[3];
    int Nt[3];
    int rowOff[3];
    int blkStart[3];
};

__device__ __forceinline__ float sigmoidf(float z) {
    return __builtin_amdgcn_rcpf(
        1.0f + __builtin_amdgcn_exp2f(-1.442695040888963f * z));
}

// Round-0 layer + compile-time K16 + depth-4 A-prefetch ring.
// Wave owns MT feature-tiles x 2 batch-tiles; A streams global->reg with a
// 4-slot rotating buffer (static indices via unroll-by-4), giving 2*MT*4
// outstanding loads per wave and a use-distance of 4 iterations — the load
// latency hides under 4 waves/SIMD of MFMA. No barriers in the K-loop.
// Register budget: acc 2*MT*16 (<=64) AGPR + ring 8*MT VGPR + b 16 + addr
// ~= 120 < 128-class -> 16 waves/CU (the round-0 occupancy).
template <int K16, int MT, bool TO_LDS>
__device__ __forceinline__ void layerP(
    unsigned short* __restrict__ buf,
    const unsigned short* __restrict__ W,
    const float* __restrict__ bias,
    int wave, int lane)
{
    const int half = lane >> 5;
    const int lr = lane & 31;

    f32x16 acc[2][MT];
#pragma unroll
    for (int n = 0; n < 2; ++n)
#pragma unroll
        for (int m = 0; m < MT; ++m)
#pragma unroll
            for (int e = 0; e < 16; ++e)
                acc[n][m][e] = 0.0f;

    const unsigned short* bp0 = buf + lr * S + half * 8;   // batch rows 0..31
    const unsigned short* bp1 = bp0 + 32 * S;              // batch rows 32..63
    const unsigned short* ap = W + (size_t)wave * MT * K16 * 512 + lane * 8;

    // prologue: fill the 4-slot ring (K16 >= 4 in all instantiations)
    bf16x8 aPf[4][MT];
#pragma unroll
    for (int d = 0; d < 4; ++d)
#pragma unroll
        for (int m = 0; m < MT; ++m)
            aPf[d][m] = *(const bf16x8*)(ap + ((size_t)m * K16 + d) * 512);

    // full iterations: consume slot u (k = kb+u), reload slot u with k+4
    for (int kb = 0; kb + 4 < K16; kb += 4) {
#pragma unroll
        for (int u = 0; u < 4; ++u) {
            int k = kb + u;
            bf16x8 b0 = *(const bf16x8*)(bp0 + k * 16);
            bf16x8 b1 = *(const bf16x8*)(bp1 + k * 16);
            bf16x8 a[MT];
#pragma unroll
            for (int m = 0; m < MT; ++m) a[m] = aPf[u][m];
#pragma unroll
            for (int m = 0; m < MT; ++m)
                aPf[u][m] =
                    *(const bf16x8*)(ap + ((size_t)m * K16 + k + 4) * 512);
#pragma unroll
            for (int m = 0; m < MT; ++m) {
                acc[0][m] = MFMA(a[m], b0, acc[0][m], 0, 0, 0);
                acc[1][m] = MFMA(a[m], b1, acc[1][m], 0, 0, 0);
            }
        }
    }
    // tail: last 4 k's, no reload (ring slots hold exactly these)
#pragma unroll
    for (int u = 0; u < 4; ++u) {
        int k = K16 - 4 + u;
        bf16x8 b0 = *(const bf16x8*)(bp0 + k * 16);
        bf16x8 b1 = *(const bf16x8*)(bp1 + k * 16);
#pragma unroll
        for (int m = 0; m < MT; ++m) {
            acc[0][m] = MFMA(aPf[u][m], b0, acc[0][m], 0, 0, 0);
            acc[1][m] = MFMA(aPf[u][m], b1, acc[1][m], 0, 0, 0);
        }
    }

    __syncthreads();   // all waves' B-reads done before in-place overwrite

#pragma unroll
    for (int m = 0; m < MT; ++m) {
        int mt = wave * MT + m;
#pragma unroll
        for (int g = 0; g < 4; ++g) {
            int f0 = mt * 32 + g * 8 + half * 4;   // 4 consecutive features
            float4 bv = *(const float4*)(bias + f0);
#pragma unroll
            for (int n = 0; n < 2; ++n) {
                int r = n * 32 + lr;
                float s0 = sigmoidf(acc[n][m][g * 4 + 0] + bv.x);
                float s1 = sigmoidf(acc[n][m][g * 4 + 1] + bv.y);
                float s2 = sigmoidf(acc[n][m][g * 4 + 2] + bv.z);
                float s3 = sigmoidf(acc[n][m][g * 4 + 3] + bv.w);
                if constexpr (TO_LDS) {
                    bf16x4 h = {(__bf16)s0, (__bf16)s1, (__bf16)s2, (__bf16)s3};
                    *(bf16x4*)(buf + r * S + f0) = h;      // packed b64
                } else {
                    float* fb = (float*)buf;
                    *(float4*)(fb + r * SF + f0) =
                        make_float4(s0, s1, s2, s3);        // b128
                }
            }
        }
    }
}

__global__ void __launch_bounds__(512, 4)   // pin 128-reg class: 16 waves/CU, 2 blocks/CU
mlp_fused(MlpParams p, float* __restrict__ out) {
    extern __shared__ unsigned short buf[];

    // bijective chunked XCD swizzle (m204)
    int nwg = gridDim.x;
    int bid = blockIdx.x;
    int q = nwg >> 3, r8 = nwg & 7;
    int xcd = bid & 7, lid = bid >> 3;
    int b = (xcd < r8 ? xcd * (q + 1) : r8 * (q + 1) + (xcd - r8) * q) + lid;

    int t = (b >= p.blkStart[1]) + (b >= p.blkStart[2]);
    int blk = b - p.blkStart[t];
    int dIn = p.dIn[t];
    int Nt = p.Nt[t];
    int row0 = blk * BM;
    const float* X = p.X[t];
    const unsigned short* W1 = p.Wp[t];
    const unsigned short* W2 = W1 + dIn * 512;
    const unsigned short* W3 = W2 + 512 * 512;

    int tid = threadIdx.x;
    int wave = tid >> 6;
    int lane = tid & 63;

    // ---- stage X (fp32 global -> bf16 LDS rows [batch][feat]) ----
    int d4 = dIn >> 2;               // float4 per row (16/32/64)
    int s4 = 31 - __clz(d4);
    int nf4 = BM * d4;
    for (int i = tid; i < nf4; i += 512) {
        int r = i >> s4;
        int c4 = i & (d4 - 1);
        int grow = row0 + r;
        float4 v = make_float4(0.f, 0.f, 0.f, 0.f);
        if (grow < Nt) v = ((const float4*)X)[(size_t)grow * d4 + c4];
        ushort4 u;
        u.x = __builtin_bit_cast(unsigned short, (__bf16)v.x);
        u.y = __builtin_bit_cast(unsigned short, (__bf16)v.y);
        u.z = __builtin_bit_cast(unsigned short, (__bf16)v.z);
        u.w = __builtin_bit_cast(unsigned short, (__bf16)v.w);
        *(ushort4*)(buf + r * S + c4 * 4) = u;
    }
    __syncthreads();

    // L1: X -> H1 in place (K16 = dIn/16, compile-time per type)
    if (t == 0)      layerP<4,  2, true>(buf, W1, p.B1[0], wave, lane);
    else if (t == 1) layerP<8,  2, true>(buf, W1, p.B1[1], wave, lane);
    else             layerP<16, 2, true>(buf, W1, p.B1[2], wave, lane);
    __syncthreads();
    // L2: H1 -> H2 in place   (512 feats)
    layerP<32, 2, true>(buf, W2, p.B2[t], wave, lane);
    __syncthreads();
    // L3: H2 -> f32 staging   (256 feats, 1 mtile/wave)
    layerP<32, 1, false>(buf, W3, p.B3[t], wave, lane);
    __syncthreads();

    // ---- coalesced output store: 64 rows x 256 f32, full 1KB rows ----
    const float* fb = (const float*)buf;
    float* gOut = out + (size_t)(p.rowOff[t] + row0) * 256;
    for (int i = tid; i < BM * 64; i += 512) {   // 4096 float4
        int r = i >> 6;
        int c4 = i & 63;
        if (row0 + r < Nt)
            *(float4*)(gOut + r * 256 + c4 * 4) =
                *(const float4*)(fb + r * SF + c4 * 4);
    }
}

// ---------------- launch ----------------
extern "C" void kernel_launch(void* const* d_in, const int* in_sizes, int n_in,
                              void* d_out, int out_size, void* d_ws, size_t ws_size,
                              hipStream_t stream) {
    const int IN0[3] = {64, 128, 256};
    const int CNT[3] = {100000, 80000, 60000};

    // ---- prepack weights into ws (bf16, A-fragment-ordered for 32x32x16) ----
    PrepParams pp;
    int blocks = 0, ubase = 0;
    for (int t = 0; t < 3; ++t) {
        int Ks[3] = {IN0[t], 512, 512};
        int Ns[3] = {512, 512, 256};
        for (int l = 0; l < 3; ++l) {
            int w = t * 3 + l;
            pp.src[w] = (const float*)d_in[4 + t * 6 + l * 2];
            pp.Kt[w] = Ks[l] >> 5;
            pp.Mg[w] = Ns[l] >> 7;
            pp.N[w] = Ns[l];
            pp.unitBase[w] = ubase;
            blocks += pp.Kt[w] * pp.Mg[w];
            pp.blkEnd[w] = blocks;
            ubase += (Ks[l] * Ns[l]) >> 3;
        }
    }
    prep_weights<<<dim3(blocks), dim3(256), 0, stream>>>(pp, (uint4*)d_ws);

    // ---- fused MLP ----
    MlpParams mp;
    int woff = 0, roff = 0, boff = 0;
    for (int t = 0; t < 3; ++t) {
        mp.X[t] = (const float*)d_in[t];
        mp.Wp[t] = (const unsigned short*)d_ws + woff;
        mp.B1[t] = (const float*)d_in[4 + t * 6 + 1];
        mp.B2[t] = (const float*)d_in[4 + t * 6 + 3];
        mp.B3[t] = (const float*)d_in[4 + t * 6 + 5];
        mp.dIn[t] = IN0[t];
        mp.Nt[t] = CNT[t];
        mp.rowOff[t] = roff;
        mp.blkStart[t] = boff;
        woff += IN0[t] * 512 + 512 * 512 + 512 * 256;
        roff += CNT[t];
        boff += (CNT[t] + BM - 1) / BM;
    }
    size_t lds = (size_t)BM * S * sizeof(unsigned short);   // 66,560 B
    mlp_fused<<<dim3(boff), dim3(512), lds, stream>>>(mp, (float*)d_out);
}

// Round 6
// 593.331 us; speedup vs baseline: 1.5621x; 1.1107x over previous
//
#include <hip/hip_runtime.h>
#include <hip/hip_bf16.h>

typedef __bf16 bf16x8 __attribute__((ext_vector_type(8)));
typedef __bf16 bf16x4 __attribute__((ext_vector_type(4)));
typedef float  f32x16 __attribute__((ext_vector_type(16)));

#define MFMA __builtin_amdgcn_mfma_f32_32x32x16_bf16
#define BM 64            // batch rows per block (2 N-tiles of 32)
#define S  520           // bf16 elems per LDS activation row (512 + 8)
#define SF 260           // f32 elems per LDS row for out staging (same 1040 B)

// ---------------- weight prepack (identical to round-0, verified) ----------
// A-operand = W^T for v_mfma_f32_32x32x16_bf16.
// A[m][k]: m = lane&31 (out-feature), k = (lane>>5)*8 + j.
// Packed unit u = unitBase[w] + ((mt*Kc + kc)*64 + lane), Kc = K/16; 8 bf16:
//   elem j = W[kc*16 + (lane>>5)*8 + j][mt*32 + (lane&31)]
struct PrepParams {
    const float* src[9];
    int Kt[9];       // K/32
    int Mg[9];       // N/128 (col groups)
    int N[9];
    int blkEnd[9];
    int unitBase[9];
};

__global__ void __launch_bounds__(256)
prep_weights(PrepParams p, uint4* __restrict__ dst) {
    __shared__ float tile[32][128];
    int b = blockIdx.x;
    int w = 0;
    while (b >= p.blkEnd[w]) ++w;
    int local = b - ((w == 0) ? 0 : p.blkEnd[w - 1]);
    int mgc = p.Mg[w];
    int kt = local / mgc;
    int mg = local - kt * mgc;
    const float* src = p.src[w];
    int N = p.N[w];
    int Kc = p.Kt[w] * 2;
    int t = threadIdx.x;

    int row0 = kt * 32, col0 = mg * 128;
#pragma unroll
    for (int i = 0; i < 4; ++i) {
        int e4 = t + i * 256;            // 1024 float4 in 32x128 tile
        int r = e4 >> 5;
        int c4 = e4 & 31;
        float4 v = *(const float4*)&src[(size_t)(row0 + r) * N + col0 + c4 * 4];
        *(float4*)&tile[r][c4 * 4] = v;
    }
    __syncthreads();

#pragma unroll
    for (int rep = 0; rep < 2; ++rep) {
        int ul = t + rep * 256;          // 512 units per block
        int lane = ul & 63;
        int kcl = (ul >> 6) & 1;
        int mtl = ul >> 7;               // 0..3
        int gUnit = p.unitBase[w] +
                    ((mg * 4 + mtl) * Kc + (kt * 2 + kcl)) * 64 + lane;
        int lr = kcl * 16 + ((lane >> 5) << 3);
        int lc = mtl * 32 + (lane & 31);
        alignas(16) unsigned short u8[8];
#pragma unroll
        for (int j = 0; j < 8; ++j)
            u8[j] = __builtin_bit_cast(unsigned short, (__bf16)tile[lr + j][lc]);
        dst[gUnit] = *(const uint4*)u8;
    }
}

// ---------------- fused MLP ----------------
struct MlpParams {
    const float* X[3];
    const unsigned short* Wp[3];
    const float* B1[3];
    const float* B2[3];
    const float* B3[3];
    int dIn[3];
    int Nt[3];
    int rowOff[3];
    int blkStart[3];
};

__device__ __forceinline__ float sigmoidf(float z) {
    return __builtin_amdgcn_rcpf(
        1.0f + __builtin_amdgcn_exp2f(-1.442695040888963f * z));
}

// Round-0 layer + compile-time K16 + depth-2 A-prefetch ring.
// Register budget is the design constraint (r4/r5 post-mortems: any spill
// adds ~350 MB HBM scratch traffic and erases the win):
//   acc 2*MT*16 <= 64 AGPR, ring 2*MT*4 = 16 VGPR, b 8, addr ~20
//   => ~110 of the 128-class -> 16 waves/CU, spill-free (r0-verified shape).
// Use-distance = 2 iterations ~= 256 cyc at 4 waves/SIMD >= L2-hit latency.
// '#pragma unroll 1' on the kb loop clamps scheduler register lookahead.
template <int K16, int MT, bool TO_LDS>
__device__ __forceinline__ void layerP(
    unsigned short* __restrict__ buf,
    const unsigned short* __restrict__ W,
    const float* __restrict__ bias,
    int wave, int lane)
{
    const int half = lane >> 5;
    const int lr = lane & 31;

    f32x16 acc[2][MT];
#pragma unroll
    for (int n = 0; n < 2; ++n)
#pragma unroll
        for (int m = 0; m < MT; ++m)
#pragma unroll
            for (int e = 0; e < 16; ++e)
                acc[n][m][e] = 0.0f;

    const unsigned short* bp0 = buf + lr * S + half * 8;   // batch rows 0..31
    const unsigned short* bp1 = bp0 + 32 * S;              // batch rows 32..63
    const unsigned short* ap = W + (size_t)wave * MT * K16 * 512 + lane * 8;

    // prologue: fill the 2-slot ring (K16 >= 4 in all instantiations)
    bf16x8 aPf[2][MT];
#pragma unroll
    for (int d = 0; d < 2; ++d)
#pragma unroll
        for (int m = 0; m < MT; ++m)
            aPf[d][m] = *(const bf16x8*)(ap + ((size_t)m * K16 + d) * 512);

    // full iterations: consume k=kb+u from slot u, reload slot u with k+2
#pragma unroll 1
    for (int kb = 0; kb + 3 < K16; kb += 2) {
#pragma unroll
        for (int u = 0; u < 2; ++u) {
            int k = kb + u;
            bf16x8 b0 = *(const bf16x8*)(bp0 + k * 16);
            bf16x8 b1 = *(const bf16x8*)(bp1 + k * 16);
            bf16x8 a[MT];
#pragma unroll
            for (int m = 0; m < MT; ++m) a[m] = aPf[u][m];
#pragma unroll
            for (int m = 0; m < MT; ++m)
                aPf[u][m] =
                    *(const bf16x8*)(ap + ((size_t)m * K16 + k + 2) * 512);
#pragma unroll
            for (int m = 0; m < MT; ++m) {
                acc[0][m] = MFMA(a[m], b0, acc[0][m], 0, 0, 0);
                acc[1][m] = MFMA(a[m], b1, acc[1][m], 0, 0, 0);
            }
        }
    }
    // tail: last 2 k's, no reload (ring slots hold exactly these)
#pragma unroll
    for (int u = 0; u < 2; ++u) {
        int k = K16 - 2 + u;
        bf16x8 b0 = *(const bf16x8*)(bp0 + k * 16);
        bf16x8 b1 = *(const bf16x8*)(bp1 + k * 16);
#pragma unroll
        for (int m = 0; m < MT; ++m) {
            acc[0][m] = MFMA(aPf[u][m], b0, acc[0][m], 0, 0, 0);
            acc[1][m] = MFMA(aPf[u][m], b1, acc[1][m], 0, 0, 0);
        }
    }

    __syncthreads();   // all waves' B-reads done before in-place overwrite

#pragma unroll
    for (int m = 0; m < MT; ++m) {
        int mt = wave * MT + m;
#pragma unroll
        for (int g = 0; g < 4; ++g) {
            int f0 = mt * 32 + g * 8 + half * 4;   // 4 consecutive features
            float4 bv = *(const float4*)(bias + f0);
#pragma unroll
            for (int n = 0; n < 2; ++n) {
                int r = n * 32 + lr;
                float s0 = sigmoidf(acc[n][m][g * 4 + 0] + bv.x);
                float s1 = sigmoidf(acc[n][m][g * 4 + 1] + bv.y);
                float s2 = sigmoidf(acc[n][m][g * 4 + 2] + bv.z);
                float s3 = sigmoidf(acc[n][m][g * 4 + 3] + bv.w);
                if constexpr (TO_LDS) {
                    bf16x4 h = {(__bf16)s0, (__bf16)s1, (__bf16)s2, (__bf16)s3};
                    *(bf16x4*)(buf + r * S + f0) = h;      // packed b64
                } else {
                    float* fb = (float*)buf;
                    *(float4*)(fb + r * SF + f0) =
                        make_float4(s0, s1, s2, s3);        // b128
                }
            }
        }
    }
}

__global__ void __launch_bounds__(512, 4)   // pin 128-reg class: 16 waves/CU, 2 blocks/CU
mlp_fused(MlpParams p, float* __restrict__ out) {
    extern __shared__ unsigned short buf[];

    // bijective chunked XCD swizzle (m204)
    int nwg = gridDim.x;
    int bid = blockIdx.x;
    int q = nwg >> 3, r8 = nwg & 7;
    int xcd = bid & 7, lid = bid >> 3;
    int b = (xcd < r8 ? xcd * (q + 1) : r8 * (q + 1) + (xcd - r8) * q) + lid;

    int t = (b >= p.blkStart[1]) + (b >= p.blkStart[2]);
    int blk = b - p.blkStart[t];
    int dIn = p.dIn[t];
    int Nt = p.Nt[t];
    int row0 = blk * BM;
    const float* X = p.X[t];
    const unsigned short* W1 = p.Wp[t];
    const unsigned short* W2 = W1 + dIn * 512;
    const unsigned short* W3 = W2 + 512 * 512;

    int tid = threadIdx.x;
    int wave = tid >> 6;
    int lane = tid & 63;

    // ---- stage X (fp32 global -> bf16 LDS rows [batch][feat]) ----
    int d4 = dIn >> 2;               // float4 per row (16/32/64)
    int s4 = 31 - __clz(d4);
    int nf4 = BM * d4;
    for (int i = tid; i < nf4; i += 512) {
        int r = i >> s4;
        int c4 = i & (d4 - 1);
        int grow = row0 + r;
        float4 v = make_float4(0.f, 0.f, 0.f, 0.f);
        if (grow < Nt) v = ((const float4*)X)[(size_t)grow * d4 + c4];
        ushort4 u;
        u.x = __builtin_bit_cast(unsigned short, (__bf16)v.x);
        u.y = __builtin_bit_cast(unsigned short, (__bf16)v.y);
        u.z = __builtin_bit_cast(unsigned short, (__bf16)v.z);
        u.w = __builtin_bit_cast(unsigned short, (__bf16)v.w);
        *(ushort4*)(buf + r * S + c4 * 4) = u;
    }
    __syncthreads();

    // L1: X -> H1 in place (K16 = dIn/16, compile-time per type)
    if (t == 0)      layerP<4,  2, true>(buf, W1, p.B1[0], wave, lane);
    else if (t == 1) layerP<8,  2, true>(buf, W1, p.B1[1], wave, lane);
    else             layerP<16, 2, true>(buf, W1, p.B1[2], wave, lane);
    __syncthreads();
    // L2: H1 -> H2 in place   (512 feats)
    layerP<32, 2, true>(buf, W2, p.B2[t], wave, lane);
    __syncthreads();
    // L3: H2 -> f32 staging   (256 feats, 1 mtile/wave)
    layerP<32, 1, false>(buf, W3, p.B3[t], wave, lane);
    __syncthreads();

    // ---- coalesced output store: 64 rows x 256 f32, full 1KB rows ----
    const float* fb = (const float*)buf;
    float* gOut = out + (size_t)(p.rowOff[t] + row0) * 256;
    for (int i = tid; i < BM * 64; i += 512) {   // 4096 float4
        int r = i >> 6;
        int c4 = i & 63;
        if (row0 + r < Nt)
            *(float4*)(gOut + r * 256 + c4 * 4) =
                *(const float4*)(fb + r * SF + c4 * 4);
    }
}

// ---------------- launch ----------------
extern "C" void kernel_launch(void* const* d_in, const int* in_sizes, int n_in,
                              void* d_out, int out_size, void* d_ws, size_t ws_size,
                              hipStream_t stream) {
    const int IN0[3] = {64, 128, 256};
    const int CNT[3] = {100000, 80000, 60000};

    // ---- prepack weights into ws (bf16, A-fragment-ordered for 32x32x16) ----
    PrepParams pp;
    int blocks = 0, ubase = 0;
    for (int t = 0; t < 3; ++t) {
        int Ks[3] = {IN0[t], 512, 512};
        int Ns[3] = {512, 512, 256};
        for (int l = 0; l < 3; ++l) {
            int w = t * 3 + l;
            pp.src[w] = (const float*)d_in[4 + t * 6 + l * 2];
            pp.Kt[w] = Ks[l] >> 5;
            pp.Mg[w] = Ns[l] >> 7;
            pp.N[w] = Ns[l];
            pp.unitBase[w] = ubase;
            blocks += pp.Kt[w] * pp.Mg[w];
            pp.blkEnd[w] = blocks;
            ubase += (Ks[l] * Ns[l]) >> 3;
        }
    }
    prep_weights<<<dim3(blocks), dim3(256), 0, stream>>>(pp, (uint4*)d_ws);

    // ---- fused MLP ----
    MlpParams mp;
    int woff = 0, roff = 0, boff = 0;
    for (int t = 0; t < 3; ++t) {
        mp.X[t] = (const float*)d_in[t];
        mp.Wp[t] = (const unsigned short*)d_ws + woff;
        mp.B1[t] = (const float*)d_in[4 + t * 6 + 1];
        mp.B2[t] = (const float*)d_in[4 + t * 6 + 3];
        mp.B3[t] = (const float*)d_in[4 + t * 6 + 5];
        mp.dIn[t] = IN0[t];
        mp.Nt[t] = CNT[t];
        mp.rowOff[t] = roff;
        mp.blkStart[t] = boff;
        woff += IN0[t] * 512 + 512 * 512 + 512 * 256;
        roff += CNT[t];
        boff += (CNT[t] + BM - 1) / BM;
    }
    size_t lds = (size_t)BM * S * sizeof(unsigned short);   // 66,560 B
    mlp_fused<<<dim3(boff), dim3(512), lds, stream>>>(mp, (float*)d_out);
}

// Round 7
// 559.556 us; speedup vs baseline: 1.6564x; 1.0604x over previous
//
#include <hip/hip_runtime.h>
#include <hip/hip_bf16.h>

typedef __bf16 bf16x8 __attribute__((ext_vector_type(8)));
typedef __bf16 bf16x4 __attribute__((ext_vector_type(4)));
typedef float  f32x16 __attribute__((ext_vector_type(16)));

#define MFMA __builtin_amdgcn_mfma_f32_32x32x16_bf16
#define BM 64            // batch rows per block (2 N-tiles of 32)
#define S  520           // bf16 elems per LDS activation row (512 + 8)
#define SF 260           // f32 elems per LDS row for out staging (same 1040 B)

// ---------------- weight prepack (identical to round-0, verified) ----------
// A-operand = W^T for v_mfma_f32_32x32x16_bf16.
// A[m][k]: m = lane&31 (out-feature), k = (lane>>5)*8 + j.
// Packed unit u = unitBase[w] + ((mt*Kc + kc)*64 + lane), Kc = K/16; 8 bf16:
//   elem j = W[kc*16 + (lane>>5)*8 + j][mt*32 + (lane&31)]
struct PrepParams {
    const float* src[9];
    int Kt[9];       // K/32
    int Mg[9];       // N/128 (col groups)
    int N[9];
    int blkEnd[9];
    int unitBase[9];
};

__global__ void __launch_bounds__(256)
prep_weights(PrepParams p, uint4* __restrict__ dst) {
    __shared__ float tile[32][128];
    int b = blockIdx.x;
    int w = 0;
    while (b >= p.blkEnd[w]) ++w;
    int local = b - ((w == 0) ? 0 : p.blkEnd[w - 1]);
    int mgc = p.Mg[w];
    int kt = local / mgc;
    int mg = local - kt * mgc;
    const float* src = p.src[w];
    int N = p.N[w];
    int Kc = p.Kt[w] * 2;
    int t = threadIdx.x;

    int row0 = kt * 32, col0 = mg * 128;
#pragma unroll
    for (int i = 0; i < 4; ++i) {
        int e4 = t + i * 256;            // 1024 float4 in 32x128 tile
        int r = e4 >> 5;
        int c4 = e4 & 31;
        float4 v = *(const float4*)&src[(size_t)(row0 + r) * N + col0 + c4 * 4];
        *(float4*)&tile[r][c4 * 4] = v;
    }
    __syncthreads();

#pragma unroll
    for (int rep = 0; rep < 2; ++rep) {
        int ul = t + rep * 256;          // 512 units per block
        int lane = ul & 63;
        int kcl = (ul >> 6) & 1;
        int mtl = ul >> 7;               // 0..3
        int gUnit = p.unitBase[w] +
                    ((mg * 4 + mtl) * Kc + (kt * 2 + kcl)) * 64 + lane;
        int lr = kcl * 16 + ((lane >> 5) << 3);
        int lc = mtl * 32 + (lane & 31);
        alignas(16) unsigned short u8[8];
#pragma unroll
        for (int j = 0; j < 8; ++j)
            u8[j] = __builtin_bit_cast(unsigned short, (__bf16)tile[lr + j][lc]);
        dst[gUnit] = *(const uint4*)u8;
    }
}

// ---------------- fused MLP ----------------
struct MlpParams {
    const float* X[3];
    const unsigned short* Wp[3];
    const float* B1[3];
    const float* B2[3];
    const float* B3[3];
    int dIn[3];
    int Nt[3];
    int rowOff[3];
};

__device__ __forceinline__ float sigmoidf(float z) {
    return __builtin_amdgcn_rcpf(
        1.0f + __builtin_amdgcn_exp2f(-1.442695040888963f * z));
}

// r6 layer (spill-free, depth-2 A-ring) + EARLY SIGMOID: bias+sigmoid is
// applied to acc in registers BEFORE the barrier (touches no LDS), so the
// VALU burst overlaps other waves'/blocks' MFMA instead of sitting in the
// barrier-serialized region. Post-barrier: pack + LDS write only.
// Register budget unchanged (in-place acc transform).
template <int K16, int MT, bool TO_LDS>
__device__ __forceinline__ void layerP(
    unsigned short* __restrict__ buf,
    const unsigned short* __restrict__ W,
    const float* __restrict__ bias,
    int wave, int lane)
{
    const int half = lane >> 5;
    const int lr = lane & 31;

    f32x16 acc[2][MT];
#pragma unroll
    for (int n = 0; n < 2; ++n)
#pragma unroll
        for (int m = 0; m < MT; ++m)
#pragma unroll
            for (int e = 0; e < 16; ++e)
                acc[n][m][e] = 0.0f;

    const unsigned short* bp0 = buf + lr * S + half * 8;   // batch rows 0..31
    const unsigned short* bp1 = bp0 + 32 * S;              // batch rows 32..63
    const unsigned short* ap = W + (size_t)wave * MT * K16 * 512 + lane * 8;

    // prologue: fill the 2-slot ring (K16 >= 4 in all instantiations)
    bf16x8 aPf[2][MT];
#pragma unroll
    for (int d = 0; d < 2; ++d)
#pragma unroll
        for (int m = 0; m < MT; ++m)
            aPf[d][m] = *(const bf16x8*)(ap + ((size_t)m * K16 + d) * 512);

    // full iterations: consume k=kb+u from slot u, reload slot u with k+2
#pragma unroll 1
    for (int kb = 0; kb + 3 < K16; kb += 2) {
#pragma unroll
        for (int u = 0; u < 2; ++u) {
            int k = kb + u;
            bf16x8 b0 = *(const bf16x8*)(bp0 + k * 16);
            bf16x8 b1 = *(const bf16x8*)(bp1 + k * 16);
            bf16x8 a[MT];
#pragma unroll
            for (int m = 0; m < MT; ++m) a[m] = aPf[u][m];
#pragma unroll
            for (int m = 0; m < MT; ++m)
                aPf[u][m] =
                    *(const bf16x8*)(ap + ((size_t)m * K16 + k + 2) * 512);
#pragma unroll
            for (int m = 0; m < MT; ++m) {
                acc[0][m] = MFMA(a[m], b0, acc[0][m], 0, 0, 0);
                acc[1][m] = MFMA(a[m], b1, acc[1][m], 0, 0, 0);
            }
        }
    }
    // tail: last 2 k's, no reload (ring slots hold exactly these)
#pragma unroll
    for (int u = 0; u < 2; ++u) {
        int k = K16 - 2 + u;
        bf16x8 b0 = *(const bf16x8*)(bp0 + k * 16);
        bf16x8 b1 = *(const bf16x8*)(bp1 + k * 16);
#pragma unroll
        for (int m = 0; m < MT; ++m) {
            acc[0][m] = MFMA(aPf[u][m], b0, acc[0][m], 0, 0, 0);
            acc[1][m] = MFMA(aPf[u][m], b1, acc[1][m], 0, 0, 0);
        }
    }

    // ---- pre-barrier: bias + sigmoid in registers (no LDS touched) ----
#pragma unroll
    for (int m = 0; m < MT; ++m) {
        int mt = wave * MT + m;
#pragma unroll
        for (int g = 0; g < 4; ++g) {
            int f0 = mt * 32 + g * 8 + half * 4;
            float4 bv = *(const float4*)(bias + f0);
#pragma unroll
            for (int n = 0; n < 2; ++n) {
                acc[n][m][g * 4 + 0] = sigmoidf(acc[n][m][g * 4 + 0] + bv.x);
                acc[n][m][g * 4 + 1] = sigmoidf(acc[n][m][g * 4 + 1] + bv.y);
                acc[n][m][g * 4 + 2] = sigmoidf(acc[n][m][g * 4 + 2] + bv.z);
                acc[n][m][g * 4 + 3] = sigmoidf(acc[n][m][g * 4 + 3] + bv.w);
            }
        }
    }

    __syncthreads();   // all waves' B-reads done before in-place overwrite

    // ---- post-barrier: pack + write only ----
#pragma unroll
    for (int m = 0; m < MT; ++m) {
        int mt = wave * MT + m;
#pragma unroll
        for (int g = 0; g < 4; ++g) {
            int f0 = mt * 32 + g * 8 + half * 4;   // 4 consecutive features
#pragma unroll
            for (int n = 0; n < 2; ++n) {
                int r = n * 32 + lr;
                if constexpr (TO_LDS) {
                    bf16x4 h = {(__bf16)acc[n][m][g * 4 + 0],
                                (__bf16)acc[n][m][g * 4 + 1],
                                (__bf16)acc[n][m][g * 4 + 2],
                                (__bf16)acc[n][m][g * 4 + 3]};
                    *(bf16x4*)(buf + r * S + f0) = h;      // packed b64
                } else {
                    float* fb = (float*)buf;
                    *(float4*)(fb + r * SF + f0) =
                        make_float4(acc[n][m][g * 4 + 0], acc[n][m][g * 4 + 1],
                                    acc[n][m][g * 4 + 2], acc[n][m][g * 4 + 3]);
                }
            }
        }
    }
}

__global__ void __launch_bounds__(512, 4)   // pin 128-reg class: 16 waves/CU, 2 blocks/CU
mlp_fused(MlpParams p, float* __restrict__ out) {
    extern __shared__ unsigned short buf[];

    // ---- type-INTERLEAVED block mapping (replaces XCD clustering) ----
    // 12-slot pattern with exact 5:4:3 type ratio: co-resident blocks are
    // (almost always) different types -> different phase durations -> the
    // two blocks on a CU stay phase-DIVERSE (MFMA of one overlaps VALU /
    // barrier-wait of the other). All 3 types' weights = 2.8MB < 4MB L2.
    // P   = [0,1,2,0,1,0,2,1,0,2,1,0]  (2-bit packed)
    // rank= [0,0,0,1,1,2,1,2,3,2,3,4]  (3-bit packed); count[t] = 5-t
    int g = blockIdx.x;
    int rep = g / 12;
    int pos = g - rep * 12;
    int t = (int)((0x186124u >> (pos * 2)) & 3u);
    int rk = (int)((0x8D3451200ULL >> (pos * 3)) & 7u);
    int blk = rep * (5 - t) + rk;

    int dIn = p.dIn[t];
    int Nt = p.Nt[t];
    int row0 = blk * BM;
    const float* X = p.X[t];
    const unsigned short* W1 = p.Wp[t];
    const unsigned short* W2 = W1 + dIn * 512;
    const unsigned short* W3 = W2 + 512 * 512;

    int tid = threadIdx.x;
    int wave = tid >> 6;
    int lane = tid & 63;

    // ---- stage X (fp32 global -> bf16 LDS rows [batch][feat]) ----
    int d4 = dIn >> 2;               // float4 per row (16/32/64)
    int s4 = 31 - __clz(d4);
    int nf4 = BM * d4;
    for (int i = tid; i < nf4; i += 512) {
        int r = i >> s4;
        int c4 = i & (d4 - 1);
        int grow = row0 + r;
        float4 v = make_float4(0.f, 0.f, 0.f, 0.f);
        if (grow < Nt) v = ((const float4*)X)[(size_t)grow * d4 + c4];
        ushort4 u;
        u.x = __builtin_bit_cast(unsigned short, (__bf16)v.x);
        u.y = __builtin_bit_cast(unsigned short, (__bf16)v.y);
        u.z = __builtin_bit_cast(unsigned short, (__bf16)v.z);
        u.w = __builtin_bit_cast(unsigned short, (__bf16)v.w);
        *(ushort4*)(buf + r * S + c4 * 4) = u;
    }
    __syncthreads();

    // L1: X -> H1 in place (K16 = dIn/16, compile-time per type)
    if (t == 0)      layerP<4,  2, true>(buf, W1, p.B1[0], wave, lane);
    else if (t == 1) layerP<8,  2, true>(buf, W1, p.B1[1], wave, lane);
    else             layerP<16, 2, true>(buf, W1, p.B1[2], wave, lane);
    __syncthreads();
    // L2: H1 -> H2 in place   (512 feats)
    layerP<32, 2, true>(buf, W2, p.B2[t], wave, lane);
    __syncthreads();
    // L3: H2 -> f32 staging   (256 feats, 1 mtile/wave)
    layerP<32, 1, false>(buf, W3, p.B3[t], wave, lane);
    __syncthreads();

    // ---- coalesced output store: 64 rows x 256 f32, full 1KB rows ----
    const float* fb = (const float*)buf;
    float* gOut = out + (size_t)(p.rowOff[t] + row0) * 256;
    for (int i = tid; i < BM * 64; i += 512) {   // 4096 float4
        int r = i >> 6;
        int c4 = i & 63;
        if (row0 + r < Nt)
            *(float4*)(gOut + r * 256 + c4 * 4) =
                *(const float4*)(fb + r * SF + c4 * 4);
    }
}

// ---------------- launch ----------------
extern "C" void kernel_launch(void* const* d_in, const int* in_sizes, int n_in,
                              void* d_out, int out_size, void* d_ws, size_t ws_size,
                              hipStream_t stream) {
    const int IN0[3] = {64, 128, 256};
    const int CNT[3] = {100000, 80000, 60000};

    // ---- prepack weights into ws (bf16, A-fragment-ordered for 32x32x16) ----
    PrepParams pp;
    int blocks = 0, ubase = 0;
    for (int t = 0; t < 3; ++t) {
        int Ks[3] = {IN0[t], 512, 512};
        int Ns[3] = {512, 512, 256};
        for (int l = 0; l < 3; ++l) {
            int w = t * 3 + l;
            pp.src[w] = (const float*)d_in[4 + t * 6 + l * 2];
            pp.Kt[w] = Ks[l] >> 5;
            pp.Mg[w] = Ns[l] >> 7;
            pp.N[w] = Ns[l];
            pp.unitBase[w] = ubase;
            blocks += pp.Kt[w] * pp.Mg[w];
            pp.blkEnd[w] = blocks;
            ubase += (Ks[l] * Ns[l]) >> 3;
        }
    }
    prep_weights<<<dim3(blocks), dim3(256), 0, stream>>>(pp, (uint4*)d_ws);

    // ---- fused MLP ----
    MlpParams mp;
    int woff = 0, roff = 0, boff = 0;
    for (int t = 0; t < 3; ++t) {
        mp.X[t] = (const float*)d_in[t];
        mp.Wp[t] = (const unsigned short*)d_ws + woff;
        mp.B1[t] = (const float*)d_in[4 + t * 6 + 1];
        mp.B2[t] = (const float*)d_in[4 + t * 6 + 3];
        mp.B3[t] = (const float*)d_in[4 + t * 6 + 5];
        mp.dIn[t] = IN0[t];
        mp.Nt[t] = CNT[t];
        mp.rowOff[t] = roff;
        woff += IN0[t] * 512 + 512 * 512 + 512 * 256;
        roff += CNT[t];
        boff += (CNT[t] + BM - 1) / BM;
    }
    size_t lds = (size_t)BM * S * sizeof(unsigned short);   // 66,560 B
    mlp_fused<<<dim3(boff), dim3(512), lds, stream>>>(mp, (float*)d_out);
}